// Round 7
// baseline (160.152 us; speedup 1.0000x reference)
//
#include <hip/hip_runtime.h>

typedef __attribute__((ext_vector_type(8))) short bf16x8;
typedef __attribute__((ext_vector_type(4))) float f32x4;
typedef __attribute__((ext_vector_type(4))) short short4v;
typedef __attribute__((ext_vector_type(4))) unsigned int u32x4;

#define DEVFN static __device__ __forceinline__

DEVFN short f2bf(float f) {
  unsigned int u = __builtin_bit_cast(unsigned int, f);
  unsigned int r = (u + 0x7FFFu + ((u >> 16) & 1u)) >> 16;   // RNE
  return (short)r;
}

DEVFN unsigned int pack2bf(float a, float b) {
  unsigned int lo = (unsigned int)(unsigned short)f2bf(a);
  unsigned int hi = (unsigned int)(unsigned short)f2bf(b);
  return lo | (hi << 16);
}

DEVFN f32x4 mfma_bf16(bf16x8 a, bf16x8 b, f32x4 c) {
  return __builtin_amdgcn_mfma_f32_16x16x32_bf16(a, b, c, 0, 0, 0);
}

DEVFN f32x4 zero4() { f32x4 z = {0.f, 0.f, 0.f, 0.f}; return z; }
DEVFN bf16x8 zero8() { bf16x8 z = {0,0,0,0,0,0,0,0}; return z; }

DEVFN void gload_lds16(const void* g, void* l) {
  __builtin_amdgcn_global_load_lds(
      (const __attribute__((address_space(1))) unsigned int*)g,
      (__attribute__((address_space(3))) unsigned int*)l, 16, 0, 0);
}

DEVFN bf16x8 lds8(const short* p) {
  short4v lo = *reinterpret_cast<const short4v*>(p);
  short4v hi = *reinterpret_cast<const short4v*>(p + 4);
  bf16x8 r;
  r[0] = lo[0]; r[1] = lo[1]; r[2] = lo[2]; r[3] = lo[3];
  r[4] = hi[0]; r[5] = hi[1]; r[6] = hi[2]; r[7] = hi[3];
  return r;
}

// ---------------------------------------------------------------------------
// Weight pack: fold BN scale, cvt bf16, fragment-major layout
// ---------------------------------------------------------------------------
__global__ void pack_w_k(const float* __restrict__ w, const float* __restrict__ g,
                         const float* __restrict__ b, const float* __restrict__ m,
                         const float* __restrict__ v, short* __restrict__ pk,
                         float* __restrict__ bias, int O) {
  const int t = blockIdx.x * 256 + threadIdx.x;
  const int nt = O >> 4;
  const int total = nt * 8 * 64;
  if (t < total) {
    int lane = t & 63;
    int j = (t >> 6) % nt;
    int c = (t >> 6) / nt;
    int row = j * 16 + (lane & 15);
    int col = c * 32 + (lane >> 4) * 8;
    float s = g[row] * rsqrtf(v[row] + 1e-5f);
    const float* wp = w + (size_t)row * 256 + col;
    short* o = pk + (size_t)t * 8;
#pragma unroll
    for (int e = 0; e < 8; ++e) o[e] = f2bf(wp[e] * s);
  }
  if (t < O) {
    float s = g[t] * rsqrtf(v[t] + 1e-5f);
    bias[t] = b[t] - m[t] * s;
  }
}

// ---------------------------------------------------------------------------
// ab_full[h][q][n] = ab_table[h][bias_idxs[q][n]]
// ---------------------------------------------------------------------------
__global__ void ab_gather_k(const float* __restrict__ tab,
                            const int* __restrict__ idxs,
                            float* __restrict__ out, int n_off) {
  const int hq = blockIdx.x;
  const int h = hq / 49, q = hq % 49;
  const int t = threadIdx.x;
  if (t < 196)
    out[(size_t)hq * 196 + t] = tab[h * n_off + idxs[q * 196 + t]];
}

// ---------------------------------------------------------------------------
// Fused producer/consumer kernel. 512 blocks (one per b), 512 thr (8 waves).
// Waves 0-3 (consumers): q-gemm, then attention head h.
// Waves 4-7 (producers): kv-gemm head h+1 into double-buffered k/v slabs.
// Attention output -> global bf16 at_out; projection is a separate kernel.
// LDS (shorts): xs[196][256]swz 50176 | qs 6272 | ks dbuf 2x3920 |
//               vs dbuf 2x(32x198+32) = 2x6368   -> total 77024 sh = 154KB
// ---------------------------------------------------------------------------
__global__ __launch_bounds__(512, 2) void fused2_k(
    const float* __restrict__ x,
    const short* __restrict__ pkv, const float* __restrict__ bkv,
    const short* __restrict__ pq,  const float* __restrict__ bq_,
    const float* __restrict__ ab,  short* __restrict__ at_out) {
  __shared__ short lds[77024];
  short* xs   = lds;           // 50176 sh
  short* qs   = lds + 50176;   //  6272 sh
  short* ksb0 = lds + 56448;   //  3920 sh
  short* ksb1 = lds + 60368;   //  3920 sh
  short* vsb0 = lds + 64288;   //  6368 sh
  short* vsb1 = lds + 70656;   //  6368 sh -> 77024

  const int b = blockIdx.x;
  const int tid = threadIdx.x, wid = tid >> 6, lane = tid & 63;
  const int l15 = lane & 15, g = lane >> 4;

  // ---- P0: zero guards/pads; stage x[b] -> bf16 LDS swizzled (all waves) ----
  if (tid < 32) vsb0[6336 + tid] = 0;
  else if (tid < 64) vsb1[6336 + (tid - 32)] = 0;
  else if (tid < 192) {
    int i = tid - 64;                    // 0..127: 2 bufs x 32 rows x 2 pad cols
    short* vb = (i < 64) ? vsb0 : vsb1;
    int row = (i >> 1) & 31;
    vb[row * 198 + 196 + (i & 1)] = 0;
  }
  const float* xb = x + (size_t)b * 196 * 256;
  for (int i = tid; i < 6272; i += 512) {
    int row = i >> 5, gc = i & 31;
    const float* src = xb + row * 256 + gc * 8;
    float4 u0 = *reinterpret_cast<const float4*>(src);
    float4 u1 = *reinterpret_cast<const float4*>(src + 4);
    bf16x8 vv;
    vv[0] = f2bf(u0.x); vv[1] = f2bf(u0.y); vv[2] = f2bf(u0.z); vv[3] = f2bf(u0.w);
    vv[4] = f2bf(u1.x); vv[5] = f2bf(u1.y); vv[6] = f2bf(u1.z); vv[7] = f2bf(u1.w);
    int ob = (gc * 16) ^ ((row & 7) << 4);
    *reinterpret_cast<bf16x8*>(reinterpret_cast<char*>(xs) + row * 512 + ob) = vv;
  }
  __syncthreads();

#define XFRAG(row, c)                                                         \
  (*reinterpret_cast<const bf16x8*>(                                          \
      reinterpret_cast<const char*>(xs) + (row) * 512 +                       \
      (((c) * 64 + g * 16) ^ (((row) & 7) << 4))))

  // ---- producer: kv-gemm for head hh into (ksd, vsd) ----
  auto kv_head = [&](int hh, short* ksd, short* vsd) {
    const int pw = wid - 4;
    bf16x8 wf0[8], wf1[8], wf2[8];
#pragma unroll
    for (int c = 0; c < 8; ++c) {
      wf0[c] = *reinterpret_cast<const bf16x8*>(pkv + ((size_t)(c * 24 + 3 * hh) * 64 + lane) * 8);
      wf1[c] = *reinterpret_cast<const bf16x8*>(pkv + ((size_t)(c * 24 + 3 * hh + 1) * 64 + lane) * 8);
      wf2[c] = *reinterpret_cast<const bf16x8*>(pkv + ((size_t)(c * 24 + 3 * hh + 2) * 64 + lane) * 8);
    }
    float  bvK = bkv[3 * hh * 16 + l15];
    float4 bv0 = *reinterpret_cast<const float4*>(bkv + (3 * hh + 1) * 16 + g * 4);
    float4 bv1 = *reinterpret_cast<const float4*>(bkv + (3 * hh + 2) * 16 + g * 4);
#pragma unroll
    for (int ti = 0; ti < 4; ++ti) {
      const int tile = pw + ti * 4;
      if (tile < 13) {
        f32x4 aK = zero4(), a0 = zero4(), a1 = zero4();
        int xr = tile * 16 + l15; if (xr > 195) xr = 195;
#pragma unroll
        for (int c = 0; c < 8; ++c) {
          bf16x8 a = XFRAG(xr, c);
          aK = mfma_bf16(a, wf0[c], aK);    // K[n][kd]
          a0 = mfma_bf16(wf1[c], a, a0);    // V^T[d0..15][n]
          a1 = mfma_bf16(wf2[c], a, a1);    // V^T[d16..31][n]
        }
#pragma unroll
        for (int r = 0; r < 4; ++r) {
          int n = tile * 16 + g * 4 + r;
          if (n < 196) ksd[n * 20 + l15] = f2bf(aK[r] + bvK);
        }
        int nv = tile * 16 + l15;
        if (nv < 196) {
#pragma unroll
          for (int r = 0; r < 4; ++r)
            vsd[(g * 4 + r) * 198 + nv] = f2bf(a0[r] + bv0[r]);
#pragma unroll
          for (int r = 0; r < 4; ++r)
            vsd[(16 + g * 4 + r) * 198 + nv] = f2bf(a1[r] + bv1[r]);
        }
      }
    }
  };

  // ---- consumer: attention for head hh ----
  auto attn_head = [&](int hh, const short* ksd, const short* vsd) {
    int qm = wid * 16 + l15; if (qm > 48) qm = 48;
    bf16x8 bq = zero8();
    if (g < 2)
      bq = *reinterpret_cast<const bf16x8*>(
          reinterpret_cast<const char*>(qs) + qm * 256 +
          ((hh * 32 + g * 16) ^ ((qm & 7) << 4)));

    f32x4 s[13];
#pragma unroll
    for (int t = 0; t < 13; ++t) {
      int n_a = (t >> 1) * 32 + (l15 >> 2) * 8 + (t & 1) * 4 + (l15 & 3);
      bf16x8 ak = zero8();
      if (g < 2 && n_a < 196) ak = lds8(ksd + n_a * 20 + g * 8);
      s[t] = mfma_bf16(ak, bq, zero4());
    }

    const float* abrow = ab + ((size_t)hh * 49 + qm) * 196;
#pragma unroll
    for (int t = 0; t < 13; ++t) {
      int nb = (t >> 1) * 32 + g * 8 + (t & 1) * 4;
      if (nb < 196) {
        const float4 bi = *reinterpret_cast<const float4*>(abrow + nb);
        s[t][0] = s[t][0] * 0.25f + bi.x;
        s[t][1] = s[t][1] * 0.25f + bi.y;
        s[t][2] = s[t][2] * 0.25f + bi.z;
        s[t][3] = s[t][3] * 0.25f + bi.w;
      } else {
        s[t][0] = -1e30f; s[t][1] = -1e30f; s[t][2] = -1e30f; s[t][3] = -1e30f;
      }
    }

    float mx = s[0][0];
#pragma unroll
    for (int t = 0; t < 13; ++t)
      mx = fmaxf(mx, fmaxf(fmaxf(s[t][0], s[t][1]), fmaxf(s[t][2], s[t][3])));
    mx = fmaxf(mx, __shfl_xor(mx, 16, 64));
    mx = fmaxf(mx, __shfl_xor(mx, 32, 64));
    float sum = 0.f;
#pragma unroll
    for (int t = 0; t < 13; ++t) {
#pragma unroll
      for (int r = 0; r < 4; ++r) {
        float e = __expf(s[t][r] - mx);
        s[t][r] = e;
        sum += e;
      }
    }
    sum += __shfl_xor(sum, 16, 64);
    sum += __shfl_xor(sum, 32, 64);
    const float inv = 1.f / sum;

    unsigned int pkr[14][2];
#pragma unroll
    for (int t = 0; t < 13; ++t) {
      pkr[t][0] = pack2bf(s[t][0] * inv, s[t][1] * inv);
      pkr[t][1] = pack2bf(s[t][2] * inv, s[t][3] * inv);
    }
    pkr[13][0] = 0u; pkr[13][1] = 0u;

    f32x4 o0 = zero4(), o1 = zero4();
#pragma unroll
    for (int c = 0; c < 7; ++c) {
      u32x4 bp_u;
      bp_u[0] = pkr[2 * c][0];     bp_u[1] = pkr[2 * c][1];
      bp_u[2] = pkr[2 * c + 1][0]; bp_u[3] = pkr[2 * c + 1][1];
      bf16x8 bp = __builtin_bit_cast(bf16x8, bp_u);
      bf16x8 v0 = lds8(vsd + l15 * 198 + c * 32 + g * 8);
      bf16x8 v1 = lds8(vsd + (16 + l15) * 198 + c * 32 + g * 8);
      o0 = mfma_bf16(bp, v0, o0);   // O[q][d], d = l15 (+16)
      o1 = mfma_bf16(bp, v1, o1);
    }

#pragma unroll
    for (int r = 0; r < 4; ++r) {
      int q2 = wid * 16 + g * 4 + r;
      if (q2 < 49) {
        float x0 = o0[r];
        float h0 = x0 * fminf(fmaxf(x0 + 3.f, 0.f), 6.f) * (1.f / 6.f);
        float x1 = o1[r];
        float h1 = x1 * fminf(fmaxf(x1 + 3.f, 0.f), 6.f) * (1.f / 6.f);
        short* op = at_out + ((size_t)b * 49 + q2) * 256 + hh * 32;
        op[l15] = f2bf(h0);
        op[16 + l15] = f2bf(h1);
      }
    }
  };

  // ---- P1: consumers q-gemm | producers kv head 0 ----
  if (wid < 4) {
    f32x4 qa[4][2];
#pragma unroll
    for (int mt = 0; mt < 4; ++mt) { qa[mt][0] = zero4(); qa[mt][1] = zero4(); }
#pragma unroll
    for (int c = 0; c < 8; ++c) {
      bf16x8 w0 = *reinterpret_cast<const bf16x8*>(pq + ((size_t)(c * 8 + 2 * wid) * 64 + lane) * 8);
      bf16x8 w1 = *reinterpret_cast<const bf16x8*>(pq + ((size_t)(c * 8 + 2 * wid + 1) * 64 + lane) * 8);
#pragma unroll
      for (int mt = 0; mt < 4; ++mt) {
        int qi = mt * 16 + l15; if (qi > 48) qi = 48;
        int xr = 28 * (qi / 7) + 2 * (qi % 7);
        bf16x8 a = XFRAG(xr, c);
        qa[mt][0] = mfma_bf16(a, w0, qa[mt][0]);
        qa[mt][1] = mfma_bf16(a, w1, qa[mt][1]);
      }
    }
#pragma unroll
    for (int mt = 0; mt < 4; ++mt) {
#pragma unroll
      for (int jj = 0; jj < 2; ++jj) {
        int ch = (2 * wid + jj) * 16 + l15;
        float bv = bq_[ch];
#pragma unroll
        for (int r = 0; r < 4; ++r) {
          int qq = mt * 16 + g * 4 + r;
          if (qq < 49)
            *reinterpret_cast<short*>(reinterpret_cast<char*>(qs) + qq * 256 +
                                      ((ch * 2) ^ ((qq & 7) << 4))) =
                f2bf(qa[mt][jj][r] + bv);
        }
      }
    }
  } else {
    kv_head(0, ksb0, vsb0);
  }
  __syncthreads();

  // ---- P2: pipelined heads — attn h (consumers) || kv h+1 (producers) ----
#pragma unroll 1
  for (int h = 0; h < 8; ++h) {
    if (wid < 4) {
      attn_head(h, (h & 1) ? ksb1 : ksb0, (h & 1) ? vsb1 : vsb0);
    } else if (h < 7) {
      kv_head(h + 1, (h & 1) ? ksb0 : ksb1, (h & 1) ? vsb0 : vsb1);
    }
    __syncthreads();
  }
#undef XFRAG
}

// ---------------------------------------------------------------------------
// Projection: out = at @ pk_p + bias -> f32 (B*49, 512). grid = 392*2.
// ---------------------------------------------------------------------------
__global__ __launch_bounds__(256) void p_gemm2(
    const short* __restrict__ a_in, const short* __restrict__ pk,
    const float* __restrict__ bias, float* __restrict__ out) {
  __shared__ short bs[16 * 512];
  __shared__ float sb[256];
  const int tid = threadIdx.x, w_id = tid >> 6, lane = tid & 63;
  const int l15 = lane & 15, gq = lane >> 4;
  const int half = blockIdx.x & 1;
  const int mt = blockIdx.x >> 1;
  for (int i = tid; i < 256; i += 256) sb[i] = bias[half * 256 + i];
  const int arow = mt * 64 + w_id * 16 + l15;
  const short* arp = a_in + (size_t)arow * 256;

  f32x4 acc[16];
#pragma unroll
  for (int j = 0; j < 16; ++j) acc[j] = zero4();

  for (int c = 0; c < 8; ++c) {
    for (int seg = w_id; seg < 16; seg += 4)
      gload_lds16(pk + ((size_t)(c * 32 + half * 16 + seg) * 64 + lane) * 8,
                  &bs[seg * 512]);
    bf16x8 a = *reinterpret_cast<const bf16x8*>(arp + c * 32 + gq * 8);
    __syncthreads();
#pragma unroll
    for (int j = 0; j < 16; ++j) {
      bf16x8 bj = *reinterpret_cast<const bf16x8*>(&bs[(j * 64 + lane) * 8]);
      acc[j] = mfma_bf16(a, bj, acc[j]);
    }
    __syncthreads();
  }
  const int orow = mt * 64 + w_id * 16 + gq * 4;
#pragma unroll
  for (int j = 0; j < 16; ++j) {
    int chl = j * 16 + l15;
    float bb = sb[chl];
    int och = half * 256 + chl;
#pragma unroll
    for (int r = 0; r < 4; ++r)
      out[(size_t)(orow + r) * 512 + och] = acc[j][r] + bb;
  }
}

// ---------------------------------------------------------------------------
extern "C" void kernel_launch(void* const* d_in, const int* in_sizes, int n_in,
                              void* d_out, int out_size, void* d_ws, size_t ws_size,
                              hipStream_t stream) {
  const float* x    = (const float*)d_in[0];
  const float* w_kv = (const float*)d_in[1];
  const float* kv_g = (const float*)d_in[2];
  const float* kv_b = (const float*)d_in[3];
  const float* kv_m = (const float*)d_in[4];
  const float* kv_v = (const float*)d_in[5];
  const float* w_q  = (const float*)d_in[6];
  const float* q_g  = (const float*)d_in[7];
  const float* q_b  = (const float*)d_in[8];
  const float* q_m  = (const float*)d_in[9];
  const float* q_v  = (const float*)d_in[10];
  const float* w_p  = (const float*)d_in[11];
  const float* p_g  = (const float*)d_in[12];
  const float* p_b  = (const float*)d_in[13];
  const float* p_m  = (const float*)d_in[14];
  const float* p_v  = (const float*)d_in[15];
  const float* ab_t = (const float*)d_in[16];
  const int*   idxs = (const int*)d_in[17];
  const int n_off = in_sizes[16] / 8;

  char* ws = (char*)d_ws;
  short* pk_kv = (short*)(ws);                 //    196,608
  short* pk_q  = (short*)(ws + 196608);        //     65,536
  short* pk_p  = (short*)(ws + 262144);        //    262,144
  float* bs_kv = (float*)(ws + 524288);        //      1,536
  float* bs_q  = (float*)(ws + 525824);        //        512
  float* bs_p  = (float*)(ws + 526336);        //      2,048
  float* ab_ws = (float*)(ws + 528384);        //    307,328 -> 835,712
  short* at_ws = (short*)(ws + 835712);        // 12,845,056 -> 13,680,768

  pack_w_k<<<dim3(48), dim3(256), 0, stream>>>(w_kv, kv_g, kv_b, kv_m, kv_v, pk_kv, bs_kv, 384);
  pack_w_k<<<dim3(16), dim3(256), 0, stream>>>(w_q, q_g, q_b, q_m, q_v, pk_q, bs_q, 128);
  pack_w_k<<<dim3(64), dim3(256), 0, stream>>>(w_p, p_g, p_b, p_m, p_v, pk_p, bs_p, 512);
  ab_gather_k<<<dim3(392), dim3(256), 0, stream>>>(ab_t, idxs, ab_ws, n_off);

  fused2_k<<<dim3(512), dim3(512), 0, stream>>>(
      x, pk_kv, bs_kv, pk_q, bs_q, ab_ws, at_ws);
  p_gemm2<<<dim3(784), dim3(256), 0, stream>>>(at_ws, pk_p, bs_p, (float*)d_out);
}